// Round 1
// baseline (2955.627 us; speedup 1.0000x reference)
//
#include <hip/hip_runtime.h>

// Conv4D: x(8,16,32,24,24,24) * W(32,16,3,3,3,3) -> out(8,32,30,22,22,22), + 3*b[o]
//
// x strides (elems):  n 7077888, c 442368, l 13824, d 576, h 24, w 1
// W strides:          o 1296, c 81, lk 27, dk 9, hk 3, wk 1
// out strides:        n 10222080, o 319440, l 10648, d 484, h 22, w 1

#define N_B   8
#define C_IN  16
#define C_OUT 32
#define L_OUT 30
#define D_OUT 22
#define H_OUT 22
#define W_OUT 22

#define X_N_STRIDE  7077888
#define X_C_STRIDE  442368
#define X_L_STRIDE  13824
#define X_D_STRIDE  576
#define O_N_STRIDE  10222080
#define O_O_STRIDE  319440
#define O_L_STRIDE  10648
#define O_D_STRIDE  484

#define W_ELEMS (32 * 1296)

// Pre-pass: W[o][r] (r = c*81+lk*27+dk*9+hk*3+wk) -> Wt[r][o] so the 32
// output-channel weights per (c,lk,dk,hk,wk) are contiguous (s_load_dwordx16).
__global__ void transpose_w_kernel(const float* __restrict__ W, float* __restrict__ Wt) {
    int i = blockIdx.x * blockDim.x + threadIdx.x;
    if (i < W_ELEMS) {
        int o = i / 1296;
        int r = i - o * 1296;
        Wt[r * 32 + o] = W[i];
    }
}

template <bool TRANSPOSED>
__global__ __launch_bounds__(512) void conv4d_kernel(
        const float* __restrict__ x,
        const float* __restrict__ wt,   // TRANSPOSED: [1296][32], else original [32][1296]
        const float* __restrict__ bias,
        float* __restrict__ out) {
    __shared__ float sx[C_IN * 576];   // one (c, h, w) slice: 16*24*24 floats = 36 KB

    const int bid = blockIdx.x;                // n * (30*22) + lo * 22 + dd
    const int n   = bid / (L_OUT * D_OUT);
    const int rem = bid - n * (L_OUT * D_OUT);
    const int lo  = rem / D_OUT;
    const int dd  = rem - lo * D_OUT;
    const int tid = threadIdx.x;

    float acc[C_OUT];
    #pragma unroll
    for (int o = 0; o < C_OUT; ++o) acc[o] = 3.0f * bias[o];  // l_k bias contributions

    const int  ho     = tid / W_OUT;
    const int  wo     = tid - ho * W_OUT;
    const bool active = tid < H_OUT * W_OUT;   // 484 compute threads

    const float* xb = x + (size_t)n * X_N_STRIDE + (size_t)lo * X_L_STRIDE + (size_t)dd * X_D_STRIDE;

    for (int lk = 0; lk < 3; ++lk) {
        for (int dk = 0; dk < 3; ++dk) {
            __syncthreads();  // protect sx from previous stage's readers
            // Stage x[n, 0:16, lo+lk, dd+dk, :, :] into LDS (float4, coalesced).
            {
                const float* src = xb + lk * X_L_STRIDE + dk * X_D_STRIDE;
                for (int e = tid * 4; e < C_IN * 576; e += 512 * 4) {
                    const int c = e / 576;
                    const int s = e - c * 576;
                    const float4 v = *reinterpret_cast<const float4*>(src + (size_t)c * X_C_STRIDE + s);
                    *reinterpret_cast<float4*>(sx + e) = v;
                }
            }
            __syncthreads();

            if (active) {
                const float* srow = sx + ho * 24 + wo;
                for (int c = 0; c < C_IN; ++c) {
                    #pragma unroll
                    for (int hk = 0; hk < 3; ++hk) {
                        #pragma unroll
                        for (int wk = 0; wk < 3; ++wk) {
                            const float xv = srow[c * 576 + hk * 24 + wk];
                            const int r = c * 81 + lk * 27 + dk * 9 + hk * 3 + wk;
                            if (TRANSPOSED) {
                                const float* wp = wt + (r << 5);
                                #pragma unroll
                                for (int o = 0; o < C_OUT; ++o)
                                    acc[o] = fmaf(xv, wp[o], acc[o]);
                            } else {
                                const float* wp = wt + r;
                                #pragma unroll
                                for (int o = 0; o < C_OUT; ++o)
                                    acc[o] = fmaf(xv, wp[o * 1296], acc[o]);
                            }
                        }
                    }
                }
            }
        }
    }

    if (active) {
        float* ob = out + (size_t)n * O_N_STRIDE + (size_t)lo * O_L_STRIDE
                  + (size_t)dd * O_D_STRIDE + ho * W_OUT + wo;
        #pragma unroll
        for (int o = 0; o < C_OUT; ++o) ob[o * O_O_STRIDE] = acc[o];
    }
}

extern "C" void kernel_launch(void* const* d_in, const int* in_sizes, int n_in,
                              void* d_out, int out_size, void* d_ws, size_t ws_size,
                              hipStream_t stream) {
    const float* x = (const float*)d_in[0];
    const float* W = (const float*)d_in[1];
    const float* b = (const float*)d_in[2];
    float* out = (float*)d_out;

    const int grid = N_B * L_OUT * D_OUT;  // 5280 blocks

    if (ws_size >= W_ELEMS * sizeof(float)) {
        float* Wt = (float*)d_ws;
        transpose_w_kernel<<<(W_ELEMS + 255) / 256, 256, 0, stream>>>(W, Wt);
        conv4d_kernel<true><<<grid, 512, 0, stream>>>(x, Wt, b, out);
    } else {
        conv4d_kernel<false><<<grid, 512, 0, stream>>>(x, W, b, out);
    }
}